// Round 1
// baseline (3876.656 us; speedup 1.0000x reference)
//
#include <hip/hip_runtime.h>
#include <stdint.h>

#define TOTAL_PULSES 4194304
#define EMB_D 64
#define N_DOMS 262144

// Workspace layout (d_ws):
//   [0, N_DOMS*64) floats              : per-dom sums
//   [N_DOMS*64, +N_DOMS) uint32        : per-dom counts
// d_out doubles as the max-pool buffer during scatter (init 0xFFFFFFFF),
// then is overwritten in place by the projection kernel.

__global__ __launch_bounds__(256) void scatter_kernel(
    const float* __restrict__ emb,
    const int* __restrict__ idx,
    float* __restrict__ sums,
    unsigned int* __restrict__ counts,
    float* __restrict__ maxv)
{
    const int lane = threadIdx.x & 63;
    const int wave = (int)((blockIdx.x * blockDim.x + threadIdx.x) >> 6);
    const int nwaves = (int)((gridDim.x * blockDim.x) >> 6);

    for (int pulse = wave; pulse < TOTAL_PULSES; pulse += nwaves) {
        int dom = idx[pulse];                       // wave-uniform, HW-broadcast
        float v = emb[(size_t)pulse * EMB_D + lane]; // coalesced 256B/wave
        size_t cell = (size_t)dom * EMB_D + lane;
        atomicAdd(&sums[cell], v);
        // float atomic-max: signed-max for v>=0, unsigned-min for v<0.
        // Init pattern 0xFFFFFFFF: signed == -1 (any pos wins), unsigned == max (any neg wins).
        if (v >= 0.0f)
            atomicMax((int*)(maxv + cell), __float_as_int(v));
        else
            atomicMin((unsigned int*)(maxv + cell), __float_as_uint(v));
        if (lane == 0)
            atomicAdd(counts + dom, 1u);
    }
}

__global__ __launch_bounds__(256) void proj_kernel(
    const float* __restrict__ sums,
    const unsigned int* __restrict__ counts,
    const float* __restrict__ w,   // (64, 128) row-major: w[j*128 + k]
    const float* __restrict__ b,   // (64,)
    float* __restrict__ out)       // in: max-pool values; out: final (N_DOMS, 64)
{
    // LDS layout: wl[(k>>2)*256 + j*4 + (k&3)] = w[j][k]
    // -> lane j reads float4 {W[4k4..4k4+3][j]} at 16B-aligned, conflict-free.
    __shared__ float wl[128 * 64];
    for (int t = threadIdx.x; t < 64 * 128; t += 256) {
        int j = t >> 7;
        int k = t & 127;
        wl[(k >> 2) * 256 + j * 4 + (k & 3)] = w[t];
    }
    __syncthreads();

    const int j = threadIdx.x & 63;
    const int wave = (int)((blockIdx.x * 256 + threadIdx.x) >> 6);
    const int nwaves = (int)(gridDim.x * 4);
    const float bj = b[j];

    for (int dom = wave; dom < N_DOMS; dom += nwaves) {
        const float4* srow = (const float4*)(sums + (size_t)dom * EMB_D);
        const float4* mrow = (const float4*)(out + (size_t)dom * EMB_D);
        unsigned int cnt = counts[dom];

        float sacc = 0.0f;
        float macc = 0.0f;
#pragma unroll
        for (int k4 = 0; k4 < 16; ++k4) {
            float4 s = srow[k4];                                   // broadcast load
            float4 ww = *(const float4*)(wl + k4 * 256 + j * 4);   // ds_read_b128
            sacc += s.x * ww.x + s.y * ww.y + s.z * ww.z + s.w * ww.w;
        }
#pragma unroll
        for (int k4 = 0; k4 < 16; ++k4) {
            float4 m = mrow[k4];                                   // broadcast load
            float4 ww = *(const float4*)(wl + (16 + k4) * 256 + j * 4);
            macc += m.x * ww.x + m.y * ww.y + m.z * ww.z + m.w * ww.w;
        }

        float inv = 1.0f / (float)((cnt > 0u) ? cnt : 1u);
        // cnt==0: sums are 0 and macc is NaN (0xFF pattern) -> select 0, result = bias.
        float res = bj + inv * sacc + ((cnt > 0u) ? macc : 0.0f);
        // In-place safe: all reads of this row happened above, row owned by this wave.
        out[(size_t)dom * EMB_D + j] = res;
    }
}

extern "C" void kernel_launch(void* const* d_in, const int* in_sizes, int n_in,
                              void* d_out, int out_size, void* d_ws, size_t ws_size,
                              hipStream_t stream) {
    const float* emb = (const float*)d_in[0];
    const int* idx = (const int*)d_in[1];
    // d_in[2] = num_doms scalar (compile-time constant here)
    const float* w = (const float*)d_in[3];
    const float* b = (const float*)d_in[4];
    float* out = (float*)d_out;

    float* sums = (float*)d_ws;
    unsigned int* counts = (unsigned int*)((char*)d_ws + (size_t)N_DOMS * EMB_D * sizeof(float));

    // Init: sums+counts = 0, max-pool (in d_out) = 0xFFFFFFFF
    hipMemsetAsync(d_ws, 0, (size_t)N_DOMS * EMB_D * sizeof(float) + (size_t)N_DOMS * sizeof(unsigned int), stream);
    hipMemsetAsync(d_out, 0xFF, (size_t)N_DOMS * EMB_D * sizeof(float), stream);

    // Scatter: one wave per pulse (grid-stride), 16384 blocks x 256 threads.
    scatter_kernel<<<16384, 256, 0, stream>>>(emb, idx, sums, counts, out);

    // Projection: 1024 blocks x 256 threads (4 waves/block, 64 doms/wave).
    proj_kernel<<<1024, 256, 0, stream>>>(sums, counts, w, b, out);
}